// Round 18
// baseline (212.587 us; speedup 1.0000x reference)
//
#include <hip/hip_runtime.h>
#include <hip/hip_bf16.h>
#include <math.h>

typedef unsigned int u32;
typedef unsigned short u16;
typedef __bf16 bf16x8 __attribute__((ext_vector_type(8)));
typedef float f32x4 __attribute__((ext_vector_type(4)));
typedef u32 u32x4 __attribute__((ext_vector_type(4)));
typedef u32 u32x2 __attribute__((ext_vector_type(2)));
typedef u16 u16x4v __attribute__((ext_vector_type(4)));

#define T_DATA 500000
#define KNO    200          // T_no (kernel length)
#define SUB    20
#define E_NO   200
#define I_NO   50
#define NBAS   13
#define PI_F   3.14159265358979f
#define KKN    7            // conv K-tiles: 7*32 = 224 window
#define P_SZ   (T_DATA*SUB) // 10,000,000
#define MT_TOT (T_DATA/16)  // 31250 (exact: no partial strips)
#define TCH    256
#define NCHUNKS_TOT ((T_DATA + TCH - 1)/TCH)   // 1954
#define GBLK   ((MT_TOT + 3)/4)                // 7813
#define WSTR   472          // conv LDS window row stride (u16)
#define SWU    3328         // gather LDS u32 per wave (13,312 B)

typedef __attribute__((address_space(1))) const u32 gas_u32;
typedef __attribute__((address_space(3))) u32 las_u32;

__device__ __forceinline__ void gll16(const void* g, u32* l){
  __builtin_amdgcn_global_load_lds((gas_u32*)g, (las_u32*)l, 16, 0, 0);
}
__device__ __forceinline__ void gll4(const void* g, u32* l){
  __builtin_amdgcn_global_load_lds((gas_u32*)g, (las_u32*)l, 4, 0, 0);
}

__device__ __forceinline__ float bf2f(u16 v){
  union { u32 u; float f; } x; x.u = ((u32)v) << 16; return x.f;
}
__device__ __forceinline__ u16 f2bf(float f){
  union { float f; u32 u; } x; x.f = f;
  u32 u = x.u;
  return (u16)((u + 0x7FFFu + ((u >> 16) & 1u)) >> 16);
}
__device__ __forceinline__ u16 trunc_bf(float f){   // exact for 0.0/1.0 spikes
  union { float f; u32 u; } x; x.f = f;
  return (u16)(x.u >> 16);
}

// kernel-bank value k_{type,s}[j];  type: 0=e,1=i,2=spk,3=hist   (all params f32)
__device__ __forceinline__ float filt_val(int type, int s, int j,
    const float* Tau, const float* Del, const float* Wsyn,
    const float* Wspk, const float* Whist){
  if (type < 2){
    float tau = Tau[s*2+type];
    float del = Del[s*2+type];
    float w   = Wsyn[s*2+type];
    float t   = fmaxf((float)j - del, 0.0f);
    float tt  = t / (tau*tau);
    float v   = tt * expf(-tt) * (w*w);
    return (type == 1) ? -v : v;
  } else {
    const float* W = (type == 2) ? Wspk : Whist;
    float raw = 3.0f * logf((float)j + 1.0f);
    float acc = 0.0f;
#pragma unroll
    for (int b = 0; b < NBAS; b++){
      float d = raw - 0.5f*PI_F*(float)b;
      float bas = (d >= -PI_F && d <= PI_F) ? (0.5f*cosf(d) + 0.5f) : 0.0f;
      acc += W[s*NBAS + b] * bas;
    }
    return acc;
  }
}

// ---- K0 merged setup: filters tail (blocks 0..79), afrag (80..639), bfrag (640..679) ----
__global__ void k_setup(const float* Tau, const float* Del, const float* Wsyn,
                        const float* Wspk, const float* Whist,
                        const float* Ce, const float* Ci,
                        float* out, u16* afrag, u16* bfrag){
  int bid = blockIdx.x;
  int tid = threadIdx.x;
  if (bid < 80){
    int r = bid, type = r / SUB, s = r % SUB;
    for (int j = tid; j < KNO; j += 64)
      out[P_SZ + r*KNO + j] = filt_val(type, s, j, Tau, Del, Wsyn, Wspk, Whist);
  } else if (bid < 80 + 4*SUB*KKN){
    int b = bid - 80;
    int kk = b % KKN;
    int ts = b / KKN;
    int type = ts / SUB, s = ts % SUB;
    __shared__ float kf[KNO];
    for (int j = tid; j < KNO; j += 64)
      kf[j] = filt_val(type, s, j, Tau, Del, Wsyn, Wspk, Whist);
    __syncthreads();
    int l = tid;
    int m = l & 15, kg = l >> 4;
    int off = 200 - 32*kk;
    u32 p[4];
#pragma unroll
    for (int h = 0; h < 4; h++){
      int u0 = kg*8 + 2*h;
      int i0 = off + m - 1 - u0;
      int i1 = i0 - 1;
      u16 lo = (i0 >= 0 && i0 < KNO) ? f2bf(kf[i0]) : (u16)0;
      u16 hi = (i1 >= 0 && i1 < KNO) ? f2bf(kf[i1]) : (u16)0;
      p[h] = (u32)lo | ((u32)hi << 16);
    }
    u32* dst = (u32*)(afrag + (size_t)b*512 + l*8);
    dst[0]=p[0]; dst[1]=p[1]; dst[2]=p[2]; dst[3]=p[3];
  } else {
    const int NE = 2*7*512, NI = 2*2*512, NZ = 2*1*512;
    int b = bid - (80 + 4*SUB*KKN);               // 0..39
    for (int x = b*64 + tid; x < NE+NI+NZ; x += 40*64){
      int src, base, KT;
      if (x < NE){ src=0; base=x;       KT=7; }
      else if (x < NE+NI){ src=1; base=x-NE;    KT=2; }
      else {               src=2; base=x-NE-NI; KT=1; }
      int nt = base / (KT*512);
      int rem = base % (KT*512);
      int kt = rem / 512;
      int le = rem % 512;
      int l = le / 8, e = le % 8;
      int n = nt*16 + (l & 15);
      int k = kt*32 + (l >> 4)*8 + e;
      u16 v = 0;
      if (src == 0){ if (n < SUB && k < E_NO) v = trunc_bf(Ce[n*E_NO + k]); }
      else if (src == 1){ if (n < SUB && k < I_NO) v = trunc_bf(Ci[n*I_NO + k]); }
      else { if (n < SUB && k == n) v = trunc_bf(1.0f); }
      bfrag[x] = v;
    }
  }
}

// ---- K1 v5: gather via MFMA; gll strip staging (linear, wave-local vmcnt) +
// ---- block-transposed coalesced C-store (tb aliases wave 0's dead sw region).
template<int W, int KT>
__device__ __forceinline__ void gather_body2(int bid, const float* __restrict__ src,
                                             const u16* __restrict__ bfrag,
                                             u16* __restrict__ dst, u32* sw,
                                             u16* tb){
  int wv = threadIdx.x >> 6, lane = threadIdx.x & 63;
  int mt = bid*4 + wv;
  bool act = (mt < MT_TOT);
  int m = lane & 15, kg = lane >> 4;

  if (act){
    const char* gb = (const char*)src + (size_t)mt*(16*W*4);
    const char* gend16 = (const char*)src + (size_t)T_DATA*W*4 - 16;
    if (W == 200){            // 12,800 B needed; stage 13 KB
#pragma unroll
      for (int j = 0; j < 13; j++){
        const char* g = gb + j*1024 + lane*16;
        if (g > gend16) g = gend16;        // final-strip over-read clamp
        gll16(g, sw + j*256);
      }
    } else if (W == 50){      // 3,200 B needed (consumed <=3,224); stage 3,328
#pragma unroll
      for (int j = 0; j < 3; j++){
        const char* g = gb + j*1024 + lane*16;
        if (g > gend16) g = gend16;
        gll16(g, sw + j*256);
      }
      {
        const char* g = gb + 3072 + lane*4;
        const char* gend4 = (const char*)src + (size_t)T_DATA*W*4 - 4;
        if (g > gend4) g = gend4;
        gll4(g, sw + 768);
      }
    } else {                  // W==20: consumed <=1,296; stage 2,048
#pragma unroll
      for (int j = 0; j < 2; j++){
        const char* g = gb + j*1024 + lane*16;
        if (g > gend16) g = gend16;
        gll16(g, sw + j*256);
      }
    }
  }
  // wave-local drain of this wave's global_load_lds ops (region is private)
  asm volatile("s_waitcnt vmcnt(0)" ::: "memory");
  __builtin_amdgcn_sched_barrier(0);   // keep ds_reads below the wait

  f32x4 acc0 = {0.f,0.f,0.f,0.f}, acc1 = {0.f,0.f,0.f,0.f};
  if (act){
#pragma unroll
    for (int kt = 0; kt < KT; kt++){
      // zero (don't read) slices whose whole 8-wide k-range is >= W: B-frag is 0
      bool skip;
      if (W == 200)      skip = (kt == 6) && (kg > 0);
      else if (W == 50)  skip = (kt == 1) && (kg == 3);
      else               skip = (kg == 3);
      union { bf16x8 v; u16 h[8]; } au;
      if (skip){
#pragma unroll
        for (int e = 0; e < 8; e++) au.h[e] = 0;
      } else {
        int fo = m*W + kt*32 + kg*8;         // u32 index into staged strip
        u32 wb[8];
        if (W == 200){                       // 16-B aligned (800m+128kt+32kg)
          *(u32x4*)&wb[0] = *(const u32x4*)(sw + fo);
          *(u32x4*)&wb[4] = *(const u32x4*)(sw + fo + 4);
        } else {                             // 8-B aligned only
          *(u32x2*)&wb[0] = *(const u32x2*)(sw + fo);
          *(u32x2*)&wb[2] = *(const u32x2*)(sw + fo + 2);
          *(u32x2*)&wb[4] = *(const u32x2*)(sw + fo + 4);
          *(u32x2*)&wb[6] = *(const u32x2*)(sw + fo + 6);
        }
#pragma unroll
        for (int e = 0; e < 8; e++) au.h[e] = (u16)(wb[e] >> 16);
      }
      bf16x8 b0 = *(const bf16x8*)(bfrag + kt*512 + lane*8);
      bf16x8 b1 = *(const bf16x8*)(bfrag + (KT + kt)*512 + lane*8);
      acc0 = __builtin_amdgcn_mfma_f32_16x16x32_bf16(au.v, b0, acc0, 0, 0, 0);
      acc1 = __builtin_amdgcn_mfma_f32_16x16x32_bf16(au.v, b1, acc1, 0, 0, 0);
    }
  }
  __syncthreads();            // all waves' fragment reads done (tb aliases sw0)

  if (act){
    // C/D: t-local = 16*wv + 4*kg + r ; channel = m (acc0), 16+m (acc1)
    int col = wv*16 + kg*4;
    u16x4v v0;
#pragma unroll
    for (int r = 0; r < 4; r++) v0[r] = f2bf(acc0[r]);
    *(u16x4v*)(tb + m*68 + col) = v0;
    if (m < SUB - 16){
      u16x4v v1;
#pragma unroll
      for (int r = 0; r < 4; r++) v1[r] = f2bf(acc1[r]);
      *(u16x4v*)(tb + (16 + m)*68 + col) = v1;
    }
  }
  __syncthreads();            // tb complete

  // cooperative coalesced store: 20 ch rows x 64 t (32 u32) per block
  long t0b = (long)bid*64;
  long remv = (T_DATA - t0b) >> 1;
  int rem32 = (remv < 32) ? (int)remv : 32;
  for (int i = threadIdx.x; i < SUB*32; i += 256){
    int ch = i >> 5, w = i & 31;
    if (w < rem32){
      u32 v = *(const u32*)(tb + ch*68 + w*2);
      ((u32*)(dst + (size_t)ch*T_DATA))[(t0b >> 1) + w] = v;
    }
  }
}

__global__ __launch_bounds__(256, 3) void k_gather_all(
    const float* __restrict__ S_e, const float* __restrict__ S_i,
    const float* __restrict__ Z, const u16* __restrict__ bfrag,
    u16* __restrict__ xe, u16* __restrict__ xi, u16* __restrict__ zt){
  __shared__ __align__(16) u32 sbuf[4*SWU];        // 53,248 B -> 3 blocks/CU
  u32* sw = sbuf + (threadIdx.x >> 6)*SWU;
  u16* tb = (u16*)sbuf;        // aliases wave 0's sw (dead after fragment reads)
  int bid = blockIdx.x;
  if (bid < GBLK)            gather_body2<200,7>(bid,          S_e, bfrag,                     xe, sw, tb);
  else if (bid < 2*GBLK)     gather_body2<50, 2>(bid - GBLK,   S_i, bfrag + 2*7*512,           xi, sw, tb);
  else                       gather_body2<20, 1>(bid - 2*GBLK, Z,   bfrag + 2*7*512 + 2*2*512, zt, sw, tb);
}

// ---- K2: LDS window stage-in (bf16 copies) + conv MFMA + mix/sigmoid epilogue ----
// (byte-identical to R13/R14/R16/R17 passing rounds)
__global__ __launch_bounds__(512, 2) void k_conv2(
    const u16* __restrict__ xe, const u16* __restrict__ xi,
    const u16* __restrict__ zt, const u16* __restrict__ afrag,
    const float* __restrict__ Cden, const float* __restrict__ Theta,
    float* __restrict__ out)
{
  __shared__ __align__(16) u16 win[3*SUB*WSTR];   // 56,640 B (window; reused for results/pbuf)
  __shared__ float lcden[SUB*SUB];
  __shared__ float lth[SUB];

  int tid = threadIdx.x;
  for (int i = tid; i < SUB*SUB; i += 512) lcden[i] = Cden[i];
  if (tid < SUB) lth[tid] = Theta[tid];

  // bijective XCD-aware chunk swizzle: consecutive chunks share an XCD L2
  int bid = blockIdx.x;
  int xcd = bid & 7, sb = bid >> 3;
  const int q8 = NCHUNKS_TOT >> 3, r8 = NCHUNKS_TOT & 7;   // 244, 2
  int c = (xcd < r8 ? xcd*(q8+1) : r8*(q8+1) + (xcd-r8)*q8) + sb;

  int wv = tid >> 6, lane = tid & 63;
  int m = lane & 15, kg = lane >> 4;
  long t0w = (long)c*TCH - 200;                   // window global t start

  // ---- stage-in: 3 arrays x 20 ch x 464 t (58 groups of 8) ----
  for (int i = tid; i < 3*SUB*58; i += 512){
    int arr = i / (SUB*58);
    int rem = i - arr*(SUB*58);
    int ch  = rem / 58;
    int i8  = rem - ch*58;
    long g0 = t0w + i8*8;
    const u16* gp = (arr == 0 ? xe : (arr == 1 ? xi : zt)) + (size_t)ch*T_DATA;
    u16* lp = win + (size_t)(arr*SUB + ch)*WSTR + i8*8;
    if (g0 >= 0 && g0 + 8 <= T_DATA){
      *(bf16x8*)lp = *(const bf16x8*)(gp + g0);
    } else {
#pragma unroll
      for (int e = 0; e < 8; e++){
        long g = g0 + e;
        lp[e] = (g >= 0 && g < T_DATA) ? gp[g] : (u16)0;
      }
    }
  }
  __syncthreads();                                // window ready

  // ---- conv via MFMA, B-operands from LDS window ----
  int boffB = 16*m + 8*kg;                        // window-local element offset
  int toff  = 16*m + 4*kg;                        // C-tile t-offset
  f32x4 A0[5], A1[5];
  if (wv < 4){
    int ch0 = wv*5;
#pragma unroll
    for (int q = 0; q < 5; q++){
      int ch = ch0 + q;
      const u16* be = win + (size_t)(0*SUB + ch)*WSTR + boffB;
      const u16* bi = win + (size_t)(1*SUB + ch)*WSTR + boffB;
      const u16* ae = afrag + (size_t)((0*SUB + ch)*KKN)*512 + lane*8;
      const u16* ai = afrag + (size_t)((1*SUB + ch)*KKN)*512 + lane*8;
      f32x4 a = {0.f,0.f,0.f,0.f};
#pragma unroll
      for (int kk = 0; kk < KKN; kk++){
        a = __builtin_amdgcn_mfma_f32_16x16x32_bf16(
              *(const bf16x8*)(ae + kk*512), *(const bf16x8*)(be + 32*kk), a, 0,0,0);
        a = __builtin_amdgcn_mfma_f32_16x16x32_bf16(
              *(const bf16x8*)(ai + kk*512), *(const bf16x8*)(bi + 32*kk), a, 0,0,0);
      }
      A0[q] = a;
    }
  } else {
    int ch0 = (wv - 4)*5;
#pragma unroll
    for (int q = 0; q < 5; q++){
      int ch = ch0 + q;
      const u16* bz = win + (size_t)(2*SUB + ch)*WSTR + boffB;
      const u16* a2 = afrag + (size_t)((2*SUB + ch)*KKN)*512 + lane*8;
      const u16* a3 = afrag + (size_t)((3*SUB + ch)*KKN)*512 + lane*8;
      f32x4 s = {0.f,0.f,0.f,0.f}, h = {0.f,0.f,0.f,0.f};
#pragma unroll
      for (int kk = 0; kk < KKN; kk++){
        bf16x8 b = *(const bf16x8*)(bz + 32*kk);
        s = __builtin_amdgcn_mfma_f32_16x16x32_bf16(*(const bf16x8*)(a2 + kk*512), b, s, 0,0,0);
        h = __builtin_amdgcn_mfma_f32_16x16x32_bf16(*(const bf16x8*)(a3 + kk*512), b, h, 0,0,0);
      }
      A0[q] = s; A1[q] = h;
    }
  }
  __syncthreads();                                // all window reads complete

  // ---- write conv results into reused LDS: rows [syn0..19][spk0..19][hist0..19] ----
  u16* rr = win;
  if (wv < 4){
#pragma unroll
    for (int q = 0; q < 5; q++){
      int ch = wv*5 + q;
      u32* d = (u32*)(rr + ch*TCH + toff);
      d[0] = (u32)f2bf(A0[q][0]) | ((u32)f2bf(A0[q][1]) << 16);
      d[1] = (u32)f2bf(A0[q][2]) | ((u32)f2bf(A0[q][3]) << 16);
    }
  } else {
#pragma unroll
    for (int q = 0; q < 5; q++){
      int ch = (wv - 4)*5 + q;
      u32* d1 = (u32*)(rr + (SUB + ch)*TCH + toff);
      d1[0] = (u32)f2bf(A0[q][0]) | ((u32)f2bf(A0[q][1]) << 16);
      d1[1] = (u32)f2bf(A0[q][2]) | ((u32)f2bf(A0[q][3]) << 16);
      u32* d2 = (u32*)(rr + (2*SUB + ch)*TCH + toff);
      d2[0] = (u32)f2bf(A1[q][0]) | ((u32)f2bf(A1[q][1]) << 16);
      d2[1] = (u32)f2bf(A1[q][2]) | ((u32)f2bf(A1[q][3]) << 16);
    }
  }
  __syncthreads();

  // ---- epilogue: P = sigmoid(syn + theta + hist + Cden @ spk) ----
  float* pbuf = (float*)win;                      // [t*21 + sp] overlay after sync
  int t = tid >> 1, h = tid & 1;
  float spkv[SUB];
#pragma unroll
  for (int s = 0; s < SUB; s++) spkv[s] = bf2f(rr[(SUB + s)*TCH + t]);
  float res[10];
#pragma unroll
  for (int j = 0; j < 10; j++){
    int sp = h*10 + j;
    float msum = bf2f(rr[sp*TCH + t]) + lth[sp] + bf2f(rr[(2*SUB + sp)*TCH + t]);
#pragma unroll
    for (int s = 0; s < SUB; s++) msum += lcden[sp*SUB + s] * spkv[s];
    res[j] = 1.0f/(1.0f + expf(-msum));
  }
  __syncthreads();               // all rr reads complete before overlay
#pragma unroll
  for (int j = 0; j < 10; j++) pbuf[t*21 + h*10 + j] = res[j];
  __syncthreads();

  // ---- fully coalesced float4 copy-out ----
  int t0c = c*TCH;
  int tv = min(TCH, T_DATA - t0c);
  int np4 = tv*SUB/4;            // 20 % 4 == 0 -> no row crossing
  for (int i = tid; i < np4; i += 512){
    int p = i*4;
    int tt = p/20, sp = p - tt*20;
    float4 v;
    v.x = pbuf[tt*21 + sp];   v.y = pbuf[tt*21 + sp+1];
    v.z = pbuf[tt*21 + sp+2]; v.w = pbuf[tt*21 + sp+3];
    *(float4*)(out + (size_t)t0c*SUB + p) = v;
  }
}

extern "C" void kernel_launch(void* const* d_in, const int* in_sizes, int n_in,
                              void* d_out, int out_size, void* d_ws, size_t ws_size,
                              hipStream_t stream){
  const float* S_e  = (const float*)d_in[0];
  const float* S_i  = (const float*)d_in[1];
  const float* Z    = (const float*)d_in[2];
  const float* Cden = (const float*)d_in[3];
  const float* C_e  = (const float*)d_in[4];
  const float* C_i  = (const float*)d_in[5];
  const float* Tau  = (const float*)d_in[6];
  const float* Del  = (const float*)d_in[7];
  const float* Wsyn = (const float*)d_in[8];
  const float* Wspk = (const float*)d_in[9];
  const float* Whist= (const float*)d_in[10];
  const float* Theta= (const float*)d_in[11];
  float* out = (float*)d_out;

  // workspace layout (bf16 elements) — R13/R14 layout
  u16* xe    = (u16*)d_ws;
  u16* xi    = xe + (size_t)SUB*T_DATA;
  u16* zt    = xi + (size_t)SUB*T_DATA;
  u16* afrag = zt + (size_t)SUB*T_DATA;            // 4*20*7*512 = 286720
  u16* bfrag = afrag + (size_t)4*SUB*KKN*512;      // 10240
  size_t need = ((size_t)3*SUB*T_DATA + (size_t)4*SUB*KKN*512 + 10240) * 2;
  if (ws_size < need) return;   // ~60.6 MB required

  k_setup<<<80 + 4*SUB*KKN + 40, 64, 0, stream>>>(
      Tau, Del, Wsyn, Wspk, Whist, C_e, C_i, out, afrag, bfrag);

  k_gather_all<<<3*GBLK, 256, 0, stream>>>(S_e, S_i, Z, bfrag, xe, xi, zt);

  k_conv2<<<NCHUNKS_TOT, 512, 0, stream>>>(xe, xi, zt, afrag, Cden, Theta, out);
}

// Round 19
// 205.786 us; speedup vs baseline: 1.0330x; 1.0330x over previous
//
#include <hip/hip_runtime.h>
#include <hip/hip_bf16.h>
#include <math.h>

typedef unsigned int u32;
typedef unsigned short u16;
typedef __bf16 bf16x8 __attribute__((ext_vector_type(8)));
typedef float f32x4 __attribute__((ext_vector_type(4)));
typedef u32 u32x4 __attribute__((ext_vector_type(4)));
typedef u32 u32x2 __attribute__((ext_vector_type(2)));

#define T_DATA 500000
#define KNO    200          // T_no (kernel length)
#define SUB    20
#define E_NO   200
#define I_NO   50
#define NBAS   13
#define PI_F   3.14159265358979f
#define KKN    7            // conv K-tiles: 7*32 = 224 window
#define P_SZ   (T_DATA*SUB) // 10,000,000
#define MT_TOT (T_DATA/16)  // 31250
#define TCH    256
#define NCHUNKS_TOT ((T_DATA + TCH - 1)/TCH)   // 1954
#define GBLK   ((MT_TOT + 3)/4)                // 7813
#define WSTR   472          // conv LDS window row stride (u16)
#define SWU    3328         // gather LDS u32 per wave (13,312 B)

typedef __attribute__((address_space(1))) const u32 gas_u32;
typedef __attribute__((address_space(3))) u32 las_u32;

__device__ __forceinline__ void gll16(const void* g, u32* l){
  __builtin_amdgcn_global_load_lds((gas_u32*)g, (las_u32*)l, 16, 0, 0);
}
__device__ __forceinline__ void gll4(const void* g, u32* l){
  __builtin_amdgcn_global_load_lds((gas_u32*)g, (las_u32*)l, 4, 0, 0);
}

__device__ __forceinline__ float bf2f(u16 v){
  union { u32 u; float f; } x; x.u = ((u32)v) << 16; return x.f;
}
__device__ __forceinline__ u16 f2bf(float f){
  union { float f; u32 u; } x; x.f = f;
  u32 u = x.u;
  return (u16)((u + 0x7FFFu + ((u >> 16) & 1u)) >> 16);
}
__device__ __forceinline__ u16 trunc_bf(float f){   // exact for 0.0/1.0 spikes
  union { float f; u32 u; } x; x.f = f;
  return (u16)(x.u >> 16);
}

// kernel-bank value k_{type,s}[j];  type: 0=e,1=i,2=spk,3=hist   (all params f32)
__device__ __forceinline__ float filt_val(int type, int s, int j,
    const float* Tau, const float* Del, const float* Wsyn,
    const float* Wspk, const float* Whist){
  if (type < 2){
    float tau = Tau[s*2+type];
    float del = Del[s*2+type];
    float w   = Wsyn[s*2+type];
    float t   = fmaxf((float)j - del, 0.0f);
    float tt  = t / (tau*tau);
    float v   = tt * expf(-tt) * (w*w);
    return (type == 1) ? -v : v;
  } else {
    const float* W = (type == 2) ? Wspk : Whist;
    float raw = 3.0f * logf((float)j + 1.0f);
    float acc = 0.0f;
#pragma unroll
    for (int b = 0; b < NBAS; b++){
      float d = raw - 0.5f*PI_F*(float)b;
      float bas = (d >= -PI_F && d <= PI_F) ? (0.5f*cosf(d) + 0.5f) : 0.0f;
      acc += W[s*NBAS + b] * bas;
    }
    return acc;
  }
}

// ---- K0 merged setup: filters tail (blocks 0..79), afrag (80..639), bfrag (640..679) ----
__global__ void k_setup(const float* Tau, const float* Del, const float* Wsyn,
                        const float* Wspk, const float* Whist,
                        const float* Ce, const float* Ci,
                        float* out, u16* afrag, u16* bfrag){
  int bid = blockIdx.x;
  int tid = threadIdx.x;
  if (bid < 80){
    int r = bid, type = r / SUB, s = r % SUB;
    for (int j = tid; j < KNO; j += 64)
      out[P_SZ + r*KNO + j] = filt_val(type, s, j, Tau, Del, Wsyn, Wspk, Whist);
  } else if (bid < 80 + 4*SUB*KKN){
    int b = bid - 80;
    int kk = b % KKN;
    int ts = b / KKN;
    int type = ts / SUB, s = ts % SUB;
    __shared__ float kf[KNO];
    for (int j = tid; j < KNO; j += 64)
      kf[j] = filt_val(type, s, j, Tau, Del, Wsyn, Wspk, Whist);
    __syncthreads();
    int l = tid;
    int m = l & 15, kg = l >> 4;
    int off = 200 - 32*kk;
    u32 p[4];
#pragma unroll
    for (int h = 0; h < 4; h++){
      int u0 = kg*8 + 2*h;
      int i0 = off + m - 1 - u0;
      int i1 = i0 - 1;
      u16 lo = (i0 >= 0 && i0 < KNO) ? f2bf(kf[i0]) : (u16)0;
      u16 hi = (i1 >= 0 && i1 < KNO) ? f2bf(kf[i1]) : (u16)0;
      p[h] = (u32)lo | ((u32)hi << 16);
    }
    u32* dst = (u32*)(afrag + (size_t)b*512 + l*8);
    dst[0]=p[0]; dst[1]=p[1]; dst[2]=p[2]; dst[3]=p[3];
  } else {
    const int NE = 2*7*512, NI = 2*2*512, NZ = 2*1*512;
    int b = bid - (80 + 4*SUB*KKN);               // 0..39
    for (int x = b*64 + tid; x < NE+NI+NZ; x += 40*64){
      int src, base, KT;
      if (x < NE){ src=0; base=x;       KT=7; }
      else if (x < NE+NI){ src=1; base=x-NE;    KT=2; }
      else {               src=2; base=x-NE-NI; KT=1; }
      int nt = base / (KT*512);
      int rem = base % (KT*512);
      int kt = rem / 512;
      int le = rem % 512;
      int l = le / 8, e = le % 8;
      int n = nt*16 + (l & 15);
      int k = kt*32 + (l >> 4)*8 + e;
      u16 v = 0;
      if (src == 0){ if (n < SUB && k < E_NO) v = trunc_bf(Ce[n*E_NO + k]); }
      else if (src == 1){ if (n < SUB && k < I_NO) v = trunc_bf(Ci[n*I_NO + k]); }
      else { if (n < SUB && k == n) v = trunc_bf(1.0f); }
      bfrag[x] = v;
    }
  }
}

// ---- K1 v4: gather via MFMA with gll strip staging, WAVE-LOCAL vmcnt wait ----
// sw regions are wave-private, so no __syncthreads needed after staging: a
// per-wave s_waitcnt vmcnt(0) suffices and decouples waves (no straggler
// rendezvous; waves stay phase-staggered -> higher HBM duty cycle).
template<int W, int KT>
__device__ __forceinline__ void gather_body2(int bid, const float* __restrict__ src,
                                             const u16* __restrict__ bfrag,
                                             u16* __restrict__ dst, u32* sw){
  int wv = threadIdx.x >> 6, lane = threadIdx.x & 63;
  int mt = bid*4 + wv;
  if (mt >= MT_TOT) return;
  int m = lane & 15, kg = lane >> 4;

  {
    const char* gb = (const char*)src + (size_t)mt*(16*W*4);
    const char* gend16 = (const char*)src + (size_t)T_DATA*W*4 - 16;
    if (W == 200){            // 12,800 B needed; stage 13 KB
#pragma unroll
      for (int j = 0; j < 13; j++){
        const char* g = gb + j*1024 + lane*16;
        if (g > gend16) g = gend16;        // final-strip over-read clamp
        gll16(g, sw + j*256);
      }
    } else if (W == 50){      // 3,200 B needed (consumed <=3,224); stage 3,328
#pragma unroll
      for (int j = 0; j < 3; j++){
        const char* g = gb + j*1024 + lane*16;
        if (g > gend16) g = gend16;
        gll16(g, sw + j*256);
      }
      {
        const char* g = gb + 3072 + lane*4;
        const char* gend4 = (const char*)src + (size_t)T_DATA*W*4 - 4;
        if (g > gend4) g = gend4;
        gll4(g, sw + 768);
      }
    } else {                  // W==20: consumed <=1,296; stage 2,048
#pragma unroll
      for (int j = 0; j < 2; j++){
        const char* g = gb + j*1024 + lane*16;
        if (g > gend16) g = gend16;
        gll16(g, sw + j*256);
      }
    }
  }
  // wave-local drain of this wave's global_load_lds ops (region is private)
  asm volatile("s_waitcnt vmcnt(0)" ::: "memory");
  __builtin_amdgcn_sched_barrier(0);   // keep ds_reads below the wait

  int t0 = mt*16;
  f32x4 acc0 = {0.f,0.f,0.f,0.f}, acc1 = {0.f,0.f,0.f,0.f};
#pragma unroll
  for (int kt = 0; kt < KT; kt++){
    // zero (don't read) slices whose whole 8-wide k-range is >= W: B-frag is 0
    bool skip;
    if (W == 200)      skip = (kt == 6) && (kg > 0);
    else if (W == 50)  skip = (kt == 1) && (kg == 3);
    else               skip = (kg == 3);
    union { bf16x8 v; u16 h[8]; } au;
    if (skip){
#pragma unroll
      for (int e = 0; e < 8; e++) au.h[e] = 0;
    } else {
      int fo = m*W + kt*32 + kg*8;         // u32 index into staged strip
      u32 wb[8];
      if (W == 200){                       // 16-B aligned (800m+128kt+32kg)
        *(u32x4*)&wb[0] = *(const u32x4*)(sw + fo);
        *(u32x4*)&wb[4] = *(const u32x4*)(sw + fo + 4);
      } else {                             // 8-B aligned only
        *(u32x2*)&wb[0] = *(const u32x2*)(sw + fo);
        *(u32x2*)&wb[2] = *(const u32x2*)(sw + fo + 2);
        *(u32x2*)&wb[4] = *(const u32x2*)(sw + fo + 4);
        *(u32x2*)&wb[6] = *(const u32x2*)(sw + fo + 6);
      }
#pragma unroll
      for (int e = 0; e < 8; e++) au.h[e] = (u16)(wb[e] >> 16);
    }
    bf16x8 b0 = *(const bf16x8*)(bfrag + kt*512 + lane*8);
    bf16x8 b1 = *(const bf16x8*)(bfrag + (KT + kt)*512 + lane*8);
    acc0 = __builtin_amdgcn_mfma_f32_16x16x32_bf16(au.v, b0, acc0, 0, 0, 0);
    acc1 = __builtin_amdgcn_mfma_f32_16x16x32_bf16(au.v, b1, acc1, 0, 0, 0);
  }
  int i0 = kg*4;   // C/D: t = 16*(lane&15) + 4*kg + reg ; channel = row block
  {
    u32 lo = (u32)f2bf(acc0[0]) | ((u32)f2bf(acc0[1]) << 16);
    u32 hi = (u32)f2bf(acc0[2]) | ((u32)f2bf(acc0[3]) << 16);
    u32* d = (u32*)(dst + (size_t)m*T_DATA + t0 + i0);
    d[0] = lo; d[1] = hi;
  }
  if (m < SUB - 16){
    u32 lo = (u32)f2bf(acc1[0]) | ((u32)f2bf(acc1[1]) << 16);
    u32 hi = (u32)f2bf(acc1[2]) | ((u32)f2bf(acc1[3]) << 16);
    u32* d = (u32*)(dst + (size_t)(16 + m)*T_DATA + t0 + i0);
    d[0] = lo; d[1] = hi;
  }
}

__global__ __launch_bounds__(256, 3) void k_gather_all(
    const float* __restrict__ S_e, const float* __restrict__ S_i,
    const float* __restrict__ Z, const u16* __restrict__ bfrag,
    u16* __restrict__ xe, u16* __restrict__ xi, u16* __restrict__ zt){
  __shared__ __align__(16) u32 sbuf[4*SWU];        // 53,248 B -> 3 blocks/CU
  u32* sw = sbuf + (threadIdx.x >> 6)*SWU;
  int bid = blockIdx.x;
  if (bid < GBLK)            gather_body2<200,7>(bid,          S_e, bfrag,                     xe, sw);
  else if (bid < 2*GBLK)     gather_body2<50, 2>(bid - GBLK,   S_i, bfrag + 2*7*512,           xi, sw);
  else                       gather_body2<20, 1>(bid - 2*GBLK, Z,   bfrag + 2*7*512 + 2*2*512, zt, sw);
}

// ---- K2: LDS window stage-in (bf16 copies) + conv MFMA + mix/sigmoid epilogue ----
// (byte-identical to R13/R14/R16/R17 passing rounds)
__global__ __launch_bounds__(512, 2) void k_conv2(
    const u16* __restrict__ xe, const u16* __restrict__ xi,
    const u16* __restrict__ zt, const u16* __restrict__ afrag,
    const float* __restrict__ Cden, const float* __restrict__ Theta,
    float* __restrict__ out)
{
  __shared__ __align__(16) u16 win[3*SUB*WSTR];   // 56,640 B (window; reused for results/pbuf)
  __shared__ float lcden[SUB*SUB];
  __shared__ float lth[SUB];

  int tid = threadIdx.x;
  for (int i = tid; i < SUB*SUB; i += 512) lcden[i] = Cden[i];
  if (tid < SUB) lth[tid] = Theta[tid];

  // bijective XCD-aware chunk swizzle: consecutive chunks share an XCD L2
  int bid = blockIdx.x;
  int xcd = bid & 7, sb = bid >> 3;
  const int q8 = NCHUNKS_TOT >> 3, r8 = NCHUNKS_TOT & 7;   // 244, 2
  int c = (xcd < r8 ? xcd*(q8+1) : r8*(q8+1) + (xcd-r8)*q8) + sb;

  int wv = tid >> 6, lane = tid & 63;
  int m = lane & 15, kg = lane >> 4;
  long t0w = (long)c*TCH - 200;                   // window global t start

  // ---- stage-in: 3 arrays x 20 ch x 464 t (58 groups of 8) ----
  for (int i = tid; i < 3*SUB*58; i += 512){
    int arr = i / (SUB*58);
    int rem = i - arr*(SUB*58);
    int ch  = rem / 58;
    int i8  = rem - ch*58;
    long g0 = t0w + i8*8;
    const u16* gp = (arr == 0 ? xe : (arr == 1 ? xi : zt)) + (size_t)ch*T_DATA;
    u16* lp = win + (size_t)(arr*SUB + ch)*WSTR + i8*8;
    if (g0 >= 0 && g0 + 8 <= T_DATA){
      *(bf16x8*)lp = *(const bf16x8*)(gp + g0);
    } else {
#pragma unroll
      for (int e = 0; e < 8; e++){
        long g = g0 + e;
        lp[e] = (g >= 0 && g < T_DATA) ? gp[g] : (u16)0;
      }
    }
  }
  __syncthreads();                                // window ready

  // ---- conv via MFMA, B-operands from LDS window ----
  int boffB = 16*m + 8*kg;                        // window-local element offset
  int toff  = 16*m + 4*kg;                        // C-tile t-offset
  f32x4 A0[5], A1[5];
  if (wv < 4){
    int ch0 = wv*5;
#pragma unroll
    for (int q = 0; q < 5; q++){
      int ch = ch0 + q;
      const u16* be = win + (size_t)(0*SUB + ch)*WSTR + boffB;
      const u16* bi = win + (size_t)(1*SUB + ch)*WSTR + boffB;
      const u16* ae = afrag + (size_t)((0*SUB + ch)*KKN)*512 + lane*8;
      const u16* ai = afrag + (size_t)((1*SUB + ch)*KKN)*512 + lane*8;
      f32x4 a = {0.f,0.f,0.f,0.f};
#pragma unroll
      for (int kk = 0; kk < KKN; kk++){
        a = __builtin_amdgcn_mfma_f32_16x16x32_bf16(
              *(const bf16x8*)(ae + kk*512), *(const bf16x8*)(be + 32*kk), a, 0,0,0);
        a = __builtin_amdgcn_mfma_f32_16x16x32_bf16(
              *(const bf16x8*)(ai + kk*512), *(const bf16x8*)(bi + 32*kk), a, 0,0,0);
      }
      A0[q] = a;
    }
  } else {
    int ch0 = (wv - 4)*5;
#pragma unroll
    for (int q = 0; q < 5; q++){
      int ch = ch0 + q;
      const u16* bz = win + (size_t)(2*SUB + ch)*WSTR + boffB;
      const u16* a2 = afrag + (size_t)((2*SUB + ch)*KKN)*512 + lane*8;
      const u16* a3 = afrag + (size_t)((3*SUB + ch)*KKN)*512 + lane*8;
      f32x4 s = {0.f,0.f,0.f,0.f}, h = {0.f,0.f,0.f,0.f};
#pragma unroll
      for (int kk = 0; kk < KKN; kk++){
        bf16x8 b = *(const bf16x8*)(bz + 32*kk);
        s = __builtin_amdgcn_mfma_f32_16x16x32_bf16(*(const bf16x8*)(a2 + kk*512), b, s, 0,0,0);
        h = __builtin_amdgcn_mfma_f32_16x16x32_bf16(*(const bf16x8*)(a3 + kk*512), b, h, 0,0,0);
      }
      A0[q] = s; A1[q] = h;
    }
  }
  __syncthreads();                                // all window reads complete

  // ---- write conv results into reused LDS: rows [syn0..19][spk0..19][hist0..19] ----
  u16* rr = win;
  if (wv < 4){
#pragma unroll
    for (int q = 0; q < 5; q++){
      int ch = wv*5 + q;
      u32* d = (u32*)(rr + ch*TCH + toff);
      d[0] = (u32)f2bf(A0[q][0]) | ((u32)f2bf(A0[q][1]) << 16);
      d[1] = (u32)f2bf(A0[q][2]) | ((u32)f2bf(A0[q][3]) << 16);
    }
  } else {
#pragma unroll
    for (int q = 0; q < 5; q++){
      int ch = (wv - 4)*5 + q;
      u32* d1 = (u32*)(rr + (SUB + ch)*TCH + toff);
      d1[0] = (u32)f2bf(A0[q][0]) | ((u32)f2bf(A0[q][1]) << 16);
      d1[1] = (u32)f2bf(A0[q][2]) | ((u32)f2bf(A0[q][3]) << 16);
      u32* d2 = (u32*)(rr + (2*SUB + ch)*TCH + toff);
      d2[0] = (u32)f2bf(A1[q][0]) | ((u32)f2bf(A1[q][1]) << 16);
      d2[1] = (u32)f2bf(A1[q][2]) | ((u32)f2bf(A1[q][3]) << 16);
    }
  }
  __syncthreads();

  // ---- epilogue: P = sigmoid(syn + theta + hist + Cden @ spk) ----
  float* pbuf = (float*)win;                      // [t*21 + sp] overlay after sync
  int t = tid >> 1, h = tid & 1;
  float spkv[SUB];
#pragma unroll
  for (int s = 0; s < SUB; s++) spkv[s] = bf2f(rr[(SUB + s)*TCH + t]);
  float res[10];
#pragma unroll
  for (int j = 0; j < 10; j++){
    int sp = h*10 + j;
    float msum = bf2f(rr[sp*TCH + t]) + lth[sp] + bf2f(rr[(2*SUB + sp)*TCH + t]);
#pragma unroll
    for (int s = 0; s < SUB; s++) msum += lcden[sp*SUB + s] * spkv[s];
    res[j] = 1.0f/(1.0f + expf(-msum));
  }
  __syncthreads();               // all rr reads complete before overlay
#pragma unroll
  for (int j = 0; j < 10; j++) pbuf[t*21 + h*10 + j] = res[j];
  __syncthreads();

  // ---- fully coalesced float4 copy-out ----
  int t0c = c*TCH;
  int tv = min(TCH, T_DATA - t0c);
  int np4 = tv*SUB/4;            // 20 % 4 == 0 -> no row crossing
  for (int i = tid; i < np4; i += 512){
    int p = i*4;
    int tt = p/20, sp = p - tt*20;
    float4 v;
    v.x = pbuf[tt*21 + sp];   v.y = pbuf[tt*21 + sp+1];
    v.z = pbuf[tt*21 + sp+2]; v.w = pbuf[tt*21 + sp+3];
    *(float4*)(out + (size_t)t0c*SUB + p) = v;
  }
}

extern "C" void kernel_launch(void* const* d_in, const int* in_sizes, int n_in,
                              void* d_out, int out_size, void* d_ws, size_t ws_size,
                              hipStream_t stream){
  const float* S_e  = (const float*)d_in[0];
  const float* S_i  = (const float*)d_in[1];
  const float* Z    = (const float*)d_in[2];
  const float* Cden = (const float*)d_in[3];
  const float* C_e  = (const float*)d_in[4];
  const float* C_i  = (const float*)d_in[5];
  const float* Tau  = (const float*)d_in[6];
  const float* Del  = (const float*)d_in[7];
  const float* Wsyn = (const float*)d_in[8];
  const float* Wspk = (const float*)d_in[9];
  const float* Whist= (const float*)d_in[10];
  const float* Theta= (const float*)d_in[11];
  float* out = (float*)d_out;

  // workspace layout (bf16 elements) — R13/R14 layout
  u16* xe    = (u16*)d_ws;
  u16* xi    = xe + (size_t)SUB*T_DATA;
  u16* zt    = xi + (size_t)SUB*T_DATA;
  u16* afrag = zt + (size_t)SUB*T_DATA;            // 4*20*7*512 = 286720
  u16* bfrag = afrag + (size_t)4*SUB*KKN*512;      // 10240
  size_t need = ((size_t)3*SUB*T_DATA + (size_t)4*SUB*KKN*512 + 10240) * 2;
  if (ws_size < need) return;   // ~60.6 MB required

  k_setup<<<80 + 4*SUB*KKN + 40, 64, 0, stream>>>(
      Tau, Del, Wsyn, Wspk, Whist, C_e, C_i, out, afrag, bfrag);

  k_gather_all<<<3*GBLK, 256, 0, stream>>>(S_e, S_i, Z, bfrag, xe, xi, zt);

  k_conv2<<<NCHUNKS_TOT, 512, 0, stream>>>(xe, xi, zt, afrag, Cden, Theta, out);
}